// Round 10
// baseline (121.828 us; speedup 1.0000x reference)
//
#include <hip/hip_runtime.h>
#include <cstdint>

typedef __bf16 bf16_t;
typedef __bf16 bf16x8 __attribute__((ext_vector_type(8)));
typedef float  f32x4  __attribute__((ext_vector_type(4)));

// Workspace layout
#define XPAD_ELEMS (32UL*58*58*128)      // padded NHWC bf16 input
#define WPERM_OFF  (XPAD_ELEMS*2)        // bytes
#define WPERM_ELEMS (256UL*9*128)        // 294912
#define WS_NEEDED  (WPERM_OFF + WPERM_ELEMS*2)

// async global->LDS, 16B per lane; lds dest is wave-uniform base + lane*16
__device__ __forceinline__ void async16(const bf16_t* g, const bf16_t* l) {
  __builtin_amdgcn_global_load_lds(
      (const __attribute__((address_space(1))) void*)g,
      (__attribute__((address_space(3))) void*)l, 16, 0, 0);
}

// ------- transpose+convert x: NCHW f32 -> padded NHWC bf16 (32,58,58,128) -------
__global__ __launch_bounds__(256) void k_xform(const float* __restrict__ x, bf16_t* __restrict__ Xp) {
  const int b = blockIdx.x;
  const int n = b / 58, hp = b % 58;
  bf16_t* drow = Xp + ((size_t)n * 58 + hp) * 58 * 128;
  const int t = threadIdx.x;
  uint4 z; z.x = z.y = z.z = z.w = 0;
  if (hp == 0 || hp == 57) {             // full border row
    uint4* p = (uint4*)drow;
    for (int i = t; i < 928; i += 256) p[i] = z;
    return;
  }
  if (t < 32) {                           // border pixels w=0 and w=57
    uint4* p0 = (uint4*)drow;
    uint4* p1 = (uint4*)(drow + 57 * 128);
    if (t < 16) p0[t] = z; else p1[t - 16] = z;
  }
  const int h = hp - 1;
  const float* src = x + (size_t)n * 401408 + h * 56;   // + c*3136 + w
  __shared__ float lds[128 * 57];
  for (int i = t; i < 7168; i += 256) {   // 128 c * 56 w
    int c = i / 56;
    int w = i - c * 56;
    lds[c * 57 + w] = src[(size_t)c * 3136 + w];
  }
  __syncthreads();
  bf16_t* dst = drow + 128;               // w starts at 1
  for (int i = t; i < 3584; i += 256) {   // pairs of channels
    int cp = i & 63, w = i >> 6;
    int c0 = cp * 2;
    unsigned short u0 = __builtin_bit_cast(unsigned short, (bf16_t)lds[c0 * 57 + w]);
    unsigned short u1 = __builtin_bit_cast(unsigned short, (bf16_t)lds[(c0 + 1) * 57 + w]);
    *(unsigned int*)(dst + (size_t)w * 128 + c0) = (unsigned)u0 | ((unsigned)u1 << 16);
  }
}

// ------- weight prepack: OIHW f32 -> Wpk[t][kc][o][e] register-fragment image -------
// i = t*8192 + kc*2048 + o*8 + e ; value = wt[o][c = ci*32 + kc*8 + e][tap rs],
// with ci = t&3, rs = t>>2. A-frag for lane(fr,fg): o = wv*64+mi*16+fr, kc = fg.
__global__ void k_wperm(const float* __restrict__ wt, bf16_t* __restrict__ Wp) {
  int i = blockIdx.x * 256 + threadIdx.x;
  if (i >= 294912) return;
  int e  = i & 7;
  int o  = (i >> 3) & 255;
  int kc = (i >> 11) & 3;
  int t  = i >> 13;
  int ci = t & 3, rs = t >> 2;
  int c  = ci * 32 + kc * 8 + e;
  Wp[i] = (bf16_t)wt[o * 1152 + c * 9 + rs];
}

// ---------------- naive fp32 fallback (only if ws too small) ----------------
__global__ void k_naive(const float* __restrict__ x, const float* __restrict__ wt,
                        const float* __restrict__ bs, float* __restrict__ out) {
  int idx = blockIdx.x * 256 + threadIdx.x;
  if (idx >= 25690112) return;
  int w = idx % 56; int tmp = idx / 56;
  int h = tmp % 56; tmp /= 56;
  int k = tmp % 256; int n = tmp / 256;
  float acc = bs[k];
  for (int c = 0; c < 128; ++c)
    for (int r = 0; r < 3; ++r) {
      int hy = h + r - 1; if ((unsigned)hy >= 56u) continue;
      for (int s = 0; s < 3; ++s) {
        int wx = w + s - 1; if ((unsigned)wx >= 56u) continue;
        acc += x[((size_t)(n * 128 + c) * 56 + hy) * 56 + wx] *
               wt[((size_t)(k * 128 + c) * 3 + r) * 3 + s];
      }
    }
  out[idx] = acc;
}

// ---------------- main conv: 8x8 patch, 25.6KB strip, 4 blocks/CU ----------------
// Block = 4 waves (256 thr); wave owns 64 out-ch x 64 px (8x8 output patch).
// B: 10x10 padded patch (25600B) staged ONCE into LDS.
//    Chunk-XOR swizzle f=(ph*8+pw)&15: each ds_read_b128's 64 lanes cover all
//    8 bank-groups exactly 8x (balanced). 4 reads feed 16 MFMA per step.
// A: reg-resident, distance-2 prefetch from L2/L1-resident Wpk.
// K-loop has NO barriers — waves free-run. 16 waves/CU (4/SIMD) at VGPR<=128.
__global__ __launch_bounds__(256, 4) void k_conv(const bf16_t* __restrict__ Xp,
                                                 const bf16_t* __restrict__ Wpk,
                                                 const float* __restrict__ bias,
                                                 float* __restrict__ out) {
  __shared__ bf16_t strip[1600 * 8];      // 25600 B: [ph10][pw10][chunk16][8ch]
  const int tid = threadIdx.x, lane = tid & 63, wv = tid >> 6;   // wv 0..3
  const int bid = (int)blockIdx.x;        // 0..1567
  const int n   = bid / 49;
  const int rem = bid - n * 49;
  const int ph0 = (rem / 7) * 8;          // padded-row origin == output-row origin
  const int pw0 = (rem % 7) * 8;

  // ---- strip staging: 6 full rounds + 64 slots (wave 0) ----
  const bf16_t* xpatch = Xp + (((size_t)n * 58 + ph0) * 58 + pw0) * 128;
#pragma unroll
  for (int rr = 0; rr < 6; ++rr) {
    int slot = rr * 256 + tid;
    int lp = slot >> 4, cp = slot & 15;   // pixel, physical chunk
    int ph = lp / 10, pw = lp - ph * 10;
    int cl = cp ^ ((ph * 8 + pw) & 15);   // logical chunk for this slot
    async16(xpatch + ((size_t)ph * 58 + pw) * 128 + cl * 8,
            strip + (rr * 256 + wv * 64) * 8);
  }
  if (wv == 0) {                          // last 64 slots
    int slot = 1536 + lane;
    int lp = slot >> 4, cp = slot & 15;
    int ph = lp / 10, pw = lp - ph * 10;
    int cl = cp ^ ((ph * 8 + pw) & 15);
    async16(xpatch + ((size_t)ph * 58 + pw) * 128 + cl * 8,
            strip + 1536 * 8);
  }

  // ---- per-lane geometry: fragment ni covers patch rows {2ni,2ni+1} x 8 cols ----
  const int fr = lane & 15, fg = lane >> 4;
  const int prl = fr >> 3, pcl = fr & 7;  // lane's row-in-pair, col
  int poff[4], fb[4];
#pragma unroll
  for (int ni = 0; ni < 4; ++ni) {
    int prow = 2 * ni + prl;
    poff[ni] = (prow * 10 + pcl) * 128;   // strip element offset of base pixel
    fb[ni]   = prow * 8 + pcl;            // swizzle base
  }

  // ---- A fragment source: wave-private 64 rows, contiguous per 16-lane group ----
  const bf16_t* wsrc = Wpk + fg * 2048 + ((wv << 6) + fr) * 8;  // + t*8192 + mi*128
  bf16x8 areg[2][4];
#pragma unroll
  for (int mi = 0; mi < 4; ++mi) {
    areg[0][mi] = *(const bf16x8*)(wsrc + mi * 128);          // t=0
    areg[1][mi] = *(const bf16x8*)(wsrc + 8192 + mi * 128);   // t=1
  }

  __syncthreads();           // strip landed (vmcnt drain) — ONLY barrier

  f32x4 acc[4][4] = {};

#pragma unroll
  for (int t = 0; t < 36; ++t) {
    const int pb = t & 1;                 // static under full unroll
    const int rs = t >> 2, ci = t & 3;
    const int r = rs / 3, s = rs - r * 3;
    const int pixAdd = (r * 10 + s) * 128;     // compile-time
    const int fAdd = r * 8 + s;                // compile-time
    const int clbase = ci * 4;                 // compile-time; chunk = clbase|fg

    bf16x8 bfr[4];
#pragma unroll
    for (int ni = 0; ni < 4; ++ni) {
      int cp = (clbase ^ fg) ^ ((fb[ni] + fAdd) & 15);   // disjoint bits: |== ^
      bfr[ni] = *(const bf16x8*)&strip[poff[ni] + pixAdd + cp * 8];
    }
    __builtin_amdgcn_s_setprio(1);
#pragma unroll
    for (int mi = 0; mi < 4; ++mi)
#pragma unroll
      for (int ni = 0; ni < 4; ++ni)
        acc[mi][ni] = __builtin_amdgcn_mfma_f32_16x16x32_bf16(areg[pb][mi], bfr[ni], acc[mi][ni], 0, 0, 0);
    __builtin_amdgcn_s_setprio(0);
    if (t + 2 < 36) {                     // distance-2 A prefetch into freed slots
#pragma unroll
      for (int mi = 0; mi < 4; ++mi)
        areg[pb][mi] = *(const bf16x8*)(wsrc + (size_t)(t + 2) * 8192 + mi * 128);
    }
  }

  // ---- epilogue: D reg j -> k = wv*64 + mi*16 + fg*4 + j, col = pixel fr ----
  const int mbase = wv * 64;
  float bv[4][4];
#pragma unroll
  for (int mi = 0; mi < 4; ++mi)
#pragma unroll
    for (int j = 0; j < 4; ++j)
      bv[mi][j] = bias[mbase + mi * 16 + fg * 4 + j];

#pragma unroll
  for (int ni = 0; ni < 4; ++ni) {
    int pr = 2 * ni + prl;                // patch row
    float* ob = out + (size_t)n * 802816 + (ph0 + pr) * 56 + (pw0 + pcl);
#pragma unroll
    for (int mi = 0; mi < 4; ++mi) {
      int kb = mbase + mi * 16 + fg * 4;
#pragma unroll
      for (int j = 0; j < 4; ++j)
        ob[(size_t)(kb + j) * 3136] = acc[mi][ni][j] + bv[mi][j];
    }
  }
}

extern "C" void kernel_launch(void* const* d_in, const int* in_sizes, int n_in,
                              void* d_out, int out_size, void* d_ws, size_t ws_size,
                              hipStream_t stream) {
  const float* x  = (const float*)d_in[0];
  const float* wt = (const float*)d_in[1];
  const float* bs = (const float*)d_in[2];
  float* out = (float*)d_out;

  if (ws_size < WS_NEEDED) {     // safety net: direct fp32 conv
    k_naive<<<(25690112 + 255) / 256, 256, 0, stream>>>(x, wt, bs, out);
    return;
  }

  bf16_t* Xp  = (bf16_t*)d_ws;
  bf16_t* Wpk = (bf16_t*)((char*)d_ws + WPERM_OFF);

  k_xform<<<1856, 256, 0, stream>>>(x, Xp);                 // 32*58 padded rows
  k_wperm<<<1152, 256, 0, stream>>>(wt, Wpk);               // 294912 / 256
  k_conv <<<1568, 256, 0, stream>>>(Xp, Wpk, bs, out);      // 32 img * 7*7 patches
}

// Round 11
// 101.945 us; speedup vs baseline: 1.1950x; 1.1950x over previous
//
#include <hip/hip_runtime.h>
#include <cstdint>

typedef __bf16 bf16_t;
typedef __bf16 bf16x8 __attribute__((ext_vector_type(8)));
typedef float  f32x4  __attribute__((ext_vector_type(4)));

// Workspace layout
#define XPAD_ELEMS (32UL*58*58*128)      // padded NHWC bf16 input
#define WPERM_OFF  (XPAD_ELEMS*2)        // bytes
#define WPERM_ELEMS (256UL*9*128)        // 294912
#define WS_NEEDED  (WPERM_OFF + WPERM_ELEMS*2)

// async global->LDS, 16B per lane; lds dest is wave-uniform base + lane*16
__device__ __forceinline__ void async16(const bf16_t* g, const bf16_t* l) {
  __builtin_amdgcn_global_load_lds(
      (const __attribute__((address_space(1))) void*)g,
      (__attribute__((address_space(3))) void*)l, 16, 0, 0);
}

// ------- transpose+convert x: NCHW f32 -> padded NHWC bf16 (32,58,58,128) -------
__global__ __launch_bounds__(256) void k_xform(const float* __restrict__ x, bf16_t* __restrict__ Xp) {
  const int b = blockIdx.x;
  const int n = b / 58, hp = b % 58;
  bf16_t* drow = Xp + ((size_t)n * 58 + hp) * 58 * 128;
  const int t = threadIdx.x;
  uint4 z; z.x = z.y = z.z = z.w = 0;
  if (hp == 0 || hp == 57) {             // full border row
    uint4* p = (uint4*)drow;
    for (int i = t; i < 928; i += 256) p[i] = z;
    return;
  }
  if (t < 32) {                           // border pixels w=0 and w=57
    uint4* p0 = (uint4*)drow;
    uint4* p1 = (uint4*)(drow + 57 * 128);
    if (t < 16) p0[t] = z; else p1[t - 16] = z;
  }
  const int h = hp - 1;
  const float* src = x + (size_t)n * 401408 + h * 56;   // + c*3136 + w
  __shared__ float lds[128 * 57];
  for (int i = t; i < 7168; i += 256) {   // 128 c * 56 w
    int c = i / 56;
    int w = i - c * 56;
    lds[c * 57 + w] = src[(size_t)c * 3136 + w];
  }
  __syncthreads();
  bf16_t* dst = drow + 128;               // w starts at 1
  for (int i = t; i < 3584; i += 256) {   // pairs of channels
    int cp = i & 63, w = i >> 6;
    int c0 = cp * 2;
    unsigned short u0 = __builtin_bit_cast(unsigned short, (bf16_t)lds[c0 * 57 + w]);
    unsigned short u1 = __builtin_bit_cast(unsigned short, (bf16_t)lds[(c0 + 1) * 57 + w]);
    *(unsigned int*)(dst + (size_t)w * 128 + c0) = (unsigned)u0 | ((unsigned)u1 << 16);
  }
}

// ------- weight prepack: OIHW f32 -> Wpk[t][kc][o][e] LDS-slice image -------
// i = t*8192 + kc*2048 + o*8 + e ; value = wt[o][c = ci*32 + kc*8 + e][tap rs],
// with ci = t&3, rs = t>>2.
__global__ void k_wperm(const float* __restrict__ wt, bf16_t* __restrict__ Wp) {
  int i = blockIdx.x * 256 + threadIdx.x;
  if (i >= 294912) return;
  int e  = i & 7;
  int o  = (i >> 3) & 255;
  int kc = (i >> 11) & 3;
  int t  = i >> 13;
  int ci = t & 3, rs = t >> 2;
  int c  = ci * 32 + kc * 8 + e;
  Wp[i] = (bf16_t)wt[o * 1152 + c * 9 + rs];
}

// ---------------- naive fp32 fallback (only if ws too small) ----------------
__global__ void k_naive(const float* __restrict__ x, const float* __restrict__ wt,
                        const float* __restrict__ bs, float* __restrict__ out) {
  int idx = blockIdx.x * 256 + threadIdx.x;
  if (idx >= 25690112) return;
  int w = idx % 56; int tmp = idx / 56;
  int h = tmp % 56; tmp /= 56;
  int k = tmp % 256; int n = tmp / 256;
  float acc = bs[k];
  for (int c = 0; c < 128; ++c)
    for (int r = 0; r < 3; ++r) {
      int hy = h + r - 1; if ((unsigned)hy >= 56u) continue;
      for (int s = 0; s < 3; ++s) {
        int wx = w + s - 1; if ((unsigned)wx >= 56u) continue;
        acc += x[((size_t)(n * 128 + c) * 56 + hy) * 56 + wx] *
               wt[((size_t)(k * 128 + c) * 3 + r) * 3 + s];
      }
    }
  out[idx] = acc;
}

// ---------------- main conv: strip-resident B + A LDS-ring (T3/T4) ----------------
// Block = 8 waves (512 thr) = 256 out-ch x 224 px (4 output rows of one image).
// B: 6-row padded strip (6x58x128ch bf16 = 89088B) staged ONCE (chunk-XOR swizzle).
// A: per-step 16KB Wpk slice in a 3-deep LDS ring, staged 2 ahead via gload_lds;
//    counted vmcnt(2) (never 0 mid-loop) + ONE s_barrier per step (T4).
// Wave (wv) = ch-group (wv>>1, 64 ch) x px-group (wv&1, 112 px): acc[4][7], 28 MFMA/step.
__global__ __launch_bounds__(512, 2) void k_conv(const bf16_t* __restrict__ Xp,
                                                 const bf16_t* __restrict__ Wpk,
                                                 const float* __restrict__ bias,
                                                 float* __restrict__ out) {
  __shared__ bf16_t strip[5568 * 8];      // 89088 B: [pix 6*58][chunk16][8ch]
  __shared__ bf16_t Alds[3][8192];        // 3 x 16 KB ring: [kc4][o256][e8]
  const int tid = threadIdx.x, lane = tid & 63, wv = tid >> 6;   // wv 0..7
  const int sid = (int)blockIdx.x;        // 0..447
  const int n   = sid / 14;
  const int h0  = (sid - n * 14) * 4;     // output-row origin == padded-row origin

  // ---- strip staging: 10 full rounds + 448 slots (waves 0..6) ----
  const bf16_t* xrow = Xp + ((size_t)n * 58 + h0) * 58 * 128;
#pragma unroll
  for (int r = 0; r < 10; ++r) {
    int slot = r * 512 + tid;
    int pix = slot >> 4, cp = slot & 15;
    int hp = pix / 58, wp = pix - hp * 58;
    int cl = cp ^ (wp & 7);               // fetch logical chunk into phys slot
    async16(xrow + ((size_t)(hp * 58 + wp)) * 128 + cl * 8,
            strip + (r * 512 + wv * 64) * 8);
  }
  if (tid < 448) {                        // waves 0..6 fully active
    int slot = 5120 + tid;
    int pix = slot >> 4, cp = slot & 15;
    int hp = pix / 58, wp = pix - hp * 58;
    int cl = cp ^ (wp & 7);
    async16(xrow + ((size_t)(hp * 58 + wp)) * 128 + cl * 8,
            strip + (5120 + wv * 64) * 8);
  }

  // ---- A-slice staging: 2 gload_lds per wave per step (1024 slots / 512 thr) ----
#define STAGE_A(buf, tt) do {                                              \
    async16(Wpk + (size_t)(tt) * 8192 + (0 * 512 + tid) * 8,               \
            &Alds[buf][(0 * 512 + wv * 64) * 8]);                          \
    async16(Wpk + (size_t)(tt) * 8192 + (1 * 512 + tid) * 8,               \
            &Alds[buf][(1 * 512 + wv * 64) * 8]);                          \
  } while (0)

  STAGE_A(0, 0);
  STAGE_A(1, 1);

  // ---- per-lane geometry ----
  const int fr = lane & 15, fg = lane >> 4;
  const int pg = wv & 1, cg = wv >> 1;    // px-group, ch-group
  int pixoff[7];
#pragma unroll
  for (int ni = 0; ni < 7; ++ni) {
    int pq = pg * 112 + ni * 16 + fr;     // tile pixel 0..223
    int oh = pq / 56;
    pixoff[ni] = (pq + 2 * oh) * 128;     // strip pixel = oh*58 + ow, elem offset
  }
  // A-frag LDS base: o = cg*64 + mi*16 + fr, kc = fg
  const int abase = (fg * 256 + cg * 64 + fr) * 8;   // + mi*128 elem

  // prologue sync: strip + A(0) landed (leave A(1)'s 2 loads in flight)
  asm volatile("s_waitcnt vmcnt(2)" ::: "memory");
  __builtin_amdgcn_s_barrier();
  __builtin_amdgcn_sched_barrier(0);

  f32x4 acc[4][7] = {};

#pragma unroll
  for (int t = 0; t < 36; ++t) {
    const int cur = t % 3;                // compile-time under full unroll
    if (t + 2 < 36) STAGE_A((t + 2) % 3, t + 2);   // writes buf[(t-1)%3]: readers done
    const int rs = t >> 2, ci = t & 3;
    const int r = rs / 3, s = rs - r * 3;
    const int pixAdd = (r * 58 + s) * 128;               // compile-time
    const int cphv = ci * 4;                             // chunk base

    bf16x8 afr[4], bfr[7];
#pragma unroll
    for (int mi = 0; mi < 4; ++mi)
      afr[mi] = *(const bf16x8*)&Alds[cur][abase + mi * 128];
#pragma unroll
    for (int ni = 0; ni < 7; ++ni) {
      int cph = (cphv + fg) ^ ((fr + s) & 7);            // 2-way floor (free)
      bfr[ni] = *(const bf16x8*)&strip[pixoff[ni] + pixAdd + cph * 8];
    }
    __builtin_amdgcn_s_setprio(1);
#pragma unroll
    for (int mi = 0; mi < 4; ++mi)
#pragma unroll
      for (int ni = 0; ni < 7; ++ni)
        acc[mi][ni] = __builtin_amdgcn_mfma_f32_16x16x32_bf16(afr[mi], bfr[ni], acc[mi][ni], 0, 0, 0);
    __builtin_amdgcn_s_setprio(0);
    if (t < 35) {                          // counted drain: stage(t+1) landed for next step
      if (t < 34) asm volatile("s_waitcnt vmcnt(2)" ::: "memory");
      else        asm volatile("s_waitcnt vmcnt(0)" ::: "memory");
      __builtin_amdgcn_s_barrier();
      __builtin_amdgcn_sched_barrier(0);
    }
  }
#undef STAGE_A

  // ---- epilogue: D reg j -> k = cg*64 + mi*16 + fg*4 + j, col = pixel fr ----
  const int mbase = cg * 64;
  float bv[4][4];
#pragma unroll
  for (int mi = 0; mi < 4; ++mi)
#pragma unroll
    for (int j = 0; j < 4; ++j)
      bv[mi][j] = bias[mbase + mi * 16 + fg * 4 + j];

#pragma unroll
  for (int ni = 0; ni < 7; ++ni) {
    int pq = pg * 112 + ni * 16 + fr;
    int oh = pq / 56;
    int ow = pq - oh * 56;
    float* ob = out + (size_t)n * 802816 + (h0 + oh) * 56 + ow;
#pragma unroll
    for (int mi = 0; mi < 4; ++mi) {
      int kb = mbase + mi * 16 + fg * 4;
#pragma unroll
      for (int j = 0; j < 4; ++j)
        ob[(size_t)(kb + j) * 3136] = acc[mi][ni][j] + bv[mi][j];
    }
  }
}

extern "C" void kernel_launch(void* const* d_in, const int* in_sizes, int n_in,
                              void* d_out, int out_size, void* d_ws, size_t ws_size,
                              hipStream_t stream) {
  const float* x  = (const float*)d_in[0];
  const float* wt = (const float*)d_in[1];
  const float* bs = (const float*)d_in[2];
  float* out = (float*)d_out;

  if (ws_size < WS_NEEDED) {     // safety net: direct fp32 conv
    k_naive<<<(25690112 + 255) / 256, 256, 0, stream>>>(x, wt, bs, out);
    return;
  }

  bf16_t* Xp  = (bf16_t*)d_ws;
  bf16_t* Wpk = (bf16_t*)((char*)d_ws + WPERM_OFF);

  k_xform<<<1856, 256, 0, stream>>>(x, Xp);                 // 32*58 padded rows
  k_wperm<<<1152, 256, 0, stream>>>(wt, Wpk);               // 294912 / 256
  k_conv <<<448, 512, 0, stream>>>(Xp, Wpk, bs, out);       // 32 img * 14 strips
}